// Round 1
// baseline (7875.408 us; speedup 1.0000x reference)
//
#include <hip/hip_runtime.h>

#define CDIV(a,b) (((a)+(b)-1)/(b))

// ---------------- degree / normalization ----------------

__global__ void init_deg_kernel(float* deg, int n) {
    int i = blockIdx.x * blockDim.x + threadIdx.x;
    if (i < n) deg[i] = 1.0f;  // self-loop contributes 1
}

__global__ void count_deg_kernel(const int* __restrict__ dst, float* deg, int E) {
    int i = blockIdx.x * blockDim.x + threadIdx.x;
    if (i < E) unsafeAtomicAdd(&deg[dst[i]], 1.0f);
}

__global__ void rsqrt_kernel(float* deg, int n) {
    int i = blockIdx.x * blockDim.x + threadIdx.x;
    if (i < n) deg[i] = rsqrtf(deg[i]);  // deg >= 1 always
}

// ---------------- dense GEMM: H[N,F] = A[N,K] @ W[K,F] ----------------
// block = 256 threads; each thread computes 4 consecutive output cols for 1 row.
// A-tile (ROWS x K = 8KB) + W-chunk (BK x F <= 32KB) staged in LDS.

template<int K, int F>
__global__ __launch_bounds__(256) void gemm_kernel(const float* __restrict__ A,
                                                   const float* __restrict__ W,
                                                   float* __restrict__ H, int N) {
    constexpr int ROWS = 1024 / F;               // 8 (F=128), 16 (F=64), 32 (F=32)
    constexpr int BKmax = 32768 / (F * 4);
    constexpr int BK = BKmax < K ? BKmax : K;
    constexpr int CPR = F / 4;                   // threads covering one row's cols

    __shared__ float As[ROWS][K];
    __shared__ float Ws[BK][F];

    const int tid = threadIdx.x;
    const int tx = tid % CPR;
    const int ty = tid / CPR;
    const int row0 = blockIdx.x * ROWS;

    // stage A tile (coalesced float4)
    constexpr int A4 = ROWS * K / 4;
    for (int t = tid; t < A4; t += 256) {
        int r = t / (K / 4);
        int c = t % (K / 4);
        int grow = row0 + r;
        float4 v = (grow < N) ? ((const float4*)(A + (long long)grow * K))[c]
                              : make_float4(0.f, 0.f, 0.f, 0.f);
        ((float4*)&As[r][0])[c] = v;
    }

    float4 acc = make_float4(0.f, 0.f, 0.f, 0.f);
    for (int kb = 0; kb < K; kb += BK) {
        __syncthreads();
        constexpr int W4 = BK * F / 4;
        for (int t = tid; t < W4; t += 256) {
            int r = t / CPR;
            int c = t % CPR;
            ((float4*)&Ws[r][0])[c] = ((const float4*)(W + (long long)(kb + r) * F))[c];
        }
        __syncthreads();
#pragma unroll 8
        for (int k = 0; k < BK; ++k) {
            float a = As[ty][kb + k];
            float4 w = ((const float4*)&Ws[k][0])[tx];
            acc.x = fmaf(a, w.x, acc.x);
            acc.y = fmaf(a, w.y, acc.y);
            acc.z = fmaf(a, w.z, acc.z);
            acc.w = fmaf(a, w.w, acc.w);
        }
    }
    int grow = row0 + ty;
    if (grow < N) ((float4*)(H + (long long)grow * F))[tx] = acc;
}

// ---------------- aggregation ----------------

// agg[i] = h[i] * dinv[i]^2   (self-loop term; also fully initializes agg)
template<int LOGF>
__global__ void init_agg_kernel(const float* __restrict__ h, const float* __restrict__ dinv,
                                float* __restrict__ agg, int n) {
    int i4 = blockIdx.x * blockDim.x + threadIdx.x;  // float4 index
    int total4 = n << (LOGF - 2);
    if (i4 >= total4) return;
    int row = i4 >> (LOGF - 2);
    float dv = dinv[row];
    float s = dv * dv;
    float4 v = ((const float4*)h)[i4];
    v.x *= s; v.y *= s; v.z *= s; v.w *= s;
    ((float4*)agg)[i4] = v;
}

// agg[dst] += h[src] * dinv[src]*dinv[dst]  via hw fp32 atomics
template<int LOGF>
__global__ void scatter_kernel(const float* __restrict__ h, const int* __restrict__ src,
                               const int* __restrict__ dst, const float* __restrict__ dinv,
                               float* agg, int E) {
    constexpr int FQ = 1 << (LOGF - 2);  // float4s per row
    long long total = (long long)E * FQ;
    long long stride = (long long)gridDim.x * blockDim.x;
    for (long long i = (long long)blockIdx.x * blockDim.x + threadIdx.x; i < total; i += stride) {
        int e  = (int)(i >> (LOGF - 2));
        int f4 = (int)(i & (FQ - 1));
        int s = src[e], d = dst[e];
        float nrm = dinv[s] * dinv[d];
        float4 v = ((const float4*)(h + ((long long)s << LOGF)))[f4];
        float* ap = agg + ((long long)d << LOGF) + f4 * 4;
        unsafeAtomicAdd(ap + 0, v.x * nrm);
        unsafeAtomicAdd(ap + 1, v.y * nrm);
        unsafeAtomicAdd(ap + 2, v.z * nrm);
        unsafeAtomicAdd(ap + 3, v.w * nrm);
    }
}

// out[i] = (agg[i] + b[f]) with optional ReLU
template<int LOGF, bool RELU>
__global__ void bias_act_kernel(const float* __restrict__ agg, const float* __restrict__ bias,
                                float* __restrict__ out, int n) {
    int i4 = blockIdx.x * blockDim.x + threadIdx.x;
    int total4 = n << (LOGF - 2);
    if (i4 >= total4) return;
    int f4 = i4 & ((1 << (LOGF - 2)) - 1);
    float4 b = ((const float4*)bias)[f4];
    float4 v = ((const float4*)agg)[i4];
    v.x += b.x; v.y += b.y; v.z += b.z; v.w += b.w;
    if (RELU) {
        v.x = fmaxf(v.x, 0.f); v.y = fmaxf(v.y, 0.f);
        v.z = fmaxf(v.z, 0.f); v.w = fmaxf(v.w, 0.f);
    }
    ((float4*)out)[i4] = v;
}

// ---------------- launcher ----------------

static inline int scatter_grid(long long total) {
    long long g = CDIV(total, 256);
    return (int)(g < 65536 ? g : 65536);
}

extern "C" void kernel_launch(void* const* d_in, const int* in_sizes, int n_in,
                              void* d_out, int out_size, void* d_ws, size_t ws_size,
                              hipStream_t stream) {
    const float* x  = (const float*)d_in[0];
    const int*   ei = (const int*)d_in[1];
    const float* W1 = (const float*)d_in[2];
    const float* b1 = (const float*)d_in[3];
    const float* W2 = (const float*)d_in[4];
    const float* b2 = (const float*)d_in[5];
    const float* W3 = (const float*)d_in[6];
    const float* b3 = (const float*)d_in[7];
    const float* W4 = (const float*)d_in[8];
    const float* b4 = (const float*)d_in[9];

    const int N = in_sizes[0] / 256;
    const int E = in_sizes[1] / 2;
    const int* src = ei;       // edge_index[0]
    const int* dst = ei + E;   // edge_index[1]

    float* dinv = (float*)d_ws;                       // N floats (deg then rsqrt in place)
    float* bufA = dinv + ((N + 255) & ~255);          // N*128 floats
    float* bufB = bufA + (size_t)N * 128;             // N*128 floats
    float* out  = (float*)d_out;

    // --- normalization coefficients ---
    init_deg_kernel<<<CDIV(N, 256), 256, 0, stream>>>(dinv, N);
    count_deg_kernel<<<CDIV(E, 256), 256, 0, stream>>>(dst, dinv, E);
    rsqrt_kernel<<<CDIV(N, 256), 256, 0, stream>>>(dinv, N);

    // --- layer 1: x[N,256] @ W1 -> 128, relu ---
    gemm_kernel<256, 128><<<CDIV(N, 8), 256, 0, stream>>>(x, W1, bufA, N);
    init_agg_kernel<7><<<CDIV(N * 32, 256), 256, 0, stream>>>(bufA, dinv, bufB, N);
    scatter_kernel<7><<<scatter_grid((long long)E * 32), 256, 0, stream>>>(bufA, src, dst, dinv, bufB, E);
    bias_act_kernel<7, true><<<CDIV(N * 32, 256), 256, 0, stream>>>(bufB, b1, bufB, N);

    // --- layer 2: [N,128] @ W2 -> 128, relu ---
    gemm_kernel<128, 128><<<CDIV(N, 8), 256, 0, stream>>>(bufB, W2, bufA, N);
    init_agg_kernel<7><<<CDIV(N * 32, 256), 256, 0, stream>>>(bufA, dinv, bufB, N);
    scatter_kernel<7><<<scatter_grid((long long)E * 32), 256, 0, stream>>>(bufA, src, dst, dinv, bufB, E);
    bias_act_kernel<7, true><<<CDIV(N * 32, 256), 256, 0, stream>>>(bufB, b2, bufB, N);

    // --- layer 3: [N,128] @ W3 -> 64, relu ---
    gemm_kernel<128, 64><<<CDIV(N, 16), 256, 0, stream>>>(bufB, W3, bufA, N);
    init_agg_kernel<6><<<CDIV(N * 16, 256), 256, 0, stream>>>(bufA, dinv, bufB, N);
    scatter_kernel<6><<<scatter_grid((long long)E * 16), 256, 0, stream>>>(bufA, src, dst, dinv, bufB, E);
    bias_act_kernel<6, true><<<CDIV(N * 16, 256), 256, 0, stream>>>(bufB, b3, bufB, N);

    // --- layer 4: [N,64] @ W4 -> 32, no relu, into d_out ---
    gemm_kernel<64, 32><<<CDIV(N, 32), 256, 0, stream>>>(bufB, W4, bufA, N);
    init_agg_kernel<5><<<CDIV(N * 8, 256), 256, 0, stream>>>(bufA, dinv, out, N);
    scatter_kernel<5><<<scatter_grid((long long)E * 8), 256, 0, stream>>>(bufA, src, dst, dinv, out, E);
    bias_act_kernel<5, false><<<CDIV(N * 8, 256), 256, 0, stream>>>(out, b4, out, N);
}

// Round 2
// 908.288 us; speedup vs baseline: 8.6706x; 8.6706x over previous
//
#include <hip/hip_runtime.h>

#define CDIV(a,b) (((a)+(b)-1)/(b))

// ---------------- CSR build: histogram, scan, bucket-fill ----------------

__global__ void zero_int_kernel(int* p, int n) {
    int i = blockIdx.x * blockDim.x + threadIdx.x;
    if (i < n) p[i] = 0;
}

__global__ void hist_kernel(const int* __restrict__ dst, int* cnt, int E) {
    int i = blockIdx.x * blockDim.x + threadIdx.x;
    if (i < E) atomicAdd(&cnt[dst[i]], 1);
}

// dinv[i] = rsqrt(deg_with_selfloop) = rsqrt(cnt[i] + 1)
__global__ void dinv_kernel(const int* __restrict__ cnt, float* dinv, int n) {
    int i = blockIdx.x * blockDim.x + threadIdx.x;
    if (i < n) dinv[i] = rsqrtf((float)cnt[i] + 1.0f);
}

// block-wise exclusive scan (512/thread-block); writes block totals to aux
__global__ __launch_bounds__(512) void scan_block_kernel(const int* __restrict__ cnt,
                                                         int* rp, int* aux, int N) {
    __shared__ int s[512];
    int t = threadIdx.x;
    int i = blockIdx.x * 512 + t;
    int v = (i < N) ? cnt[i] : 0;
    s[t] = v;
    __syncthreads();
    for (int off = 1; off < 512; off <<= 1) {
        int x = (t >= off) ? s[t - off] : 0;
        __syncthreads();
        s[t] += x;
        __syncthreads();
    }
    if (i < N) rp[i] = s[t] - v;           // exclusive within block
    if (t == 511) aux[blockIdx.x] = s[511]; // block total
}

// single-block exclusive scan of block totals (nb <= 256)
__global__ __launch_bounds__(256) void scan_aux_kernel(int* aux, int nb) {
    __shared__ int s[256];
    int t = threadIdx.x;
    int v = (t < nb) ? aux[t] : 0;
    s[t] = v;
    __syncthreads();
    for (int off = 1; off < 256; off <<= 1) {
        int x = (t >= off) ? s[t - off] : 0;
        __syncthreads();
        s[t] += x;
        __syncthreads();
    }
    if (t < nb) aux[t] = s[t] - v;         // exclusive
}

__global__ void scan_add_kernel(int* rp, const int* __restrict__ aux, int N, int E) {
    int i = blockIdx.x * blockDim.x + threadIdx.x;
    if (i < N) rp[i] += aux[i >> 9];
    if (i == N) rp[N] = E;
}

__global__ void fill_csr_kernel(const int* __restrict__ src, const int* __restrict__ dst,
                                const int* __restrict__ rp, int* fill, int* col, int E) {
    int e = blockIdx.x * blockDim.x + threadIdx.x;
    if (e >= E) return;
    int d = dst[e];
    int pos = rp[d] + atomicAdd(&fill[d], 1);
    col[pos] = src[e];
}

// ---------------- dense GEMM: H[N,F] = A[N,K] @ W[K,F] ----------------

template<int K, int F>
__global__ __launch_bounds__(256) void gemm_kernel(const float* __restrict__ A,
                                                   const float* __restrict__ W,
                                                   float* __restrict__ H, int N) {
    constexpr int ROWS = 1024 / F;
    constexpr int BKmax = 32768 / (F * 4);
    constexpr int BK = BKmax < K ? BKmax : K;
    constexpr int CPR = F / 4;

    __shared__ float As[ROWS][K];
    __shared__ float Ws[BK][F];

    const int tid = threadIdx.x;
    const int tx = tid % CPR;
    const int ty = tid / CPR;
    const int row0 = blockIdx.x * ROWS;

    constexpr int A4 = ROWS * K / 4;
    for (int t = tid; t < A4; t += 256) {
        int r = t / (K / 4);
        int c = t % (K / 4);
        int grow = row0 + r;
        float4 v = (grow < N) ? ((const float4*)(A + (long long)grow * K))[c]
                              : make_float4(0.f, 0.f, 0.f, 0.f);
        ((float4*)&As[r][0])[c] = v;
    }

    float4 acc = make_float4(0.f, 0.f, 0.f, 0.f);
    for (int kb = 0; kb < K; kb += BK) {
        __syncthreads();
        constexpr int W4 = BK * F / 4;
        for (int t = tid; t < W4; t += 256) {
            int r = t / CPR;
            int c = t % CPR;
            ((float4*)&Ws[r][0])[c] = ((const float4*)(W + (long long)(kb + r) * F))[c];
        }
        __syncthreads();
#pragma unroll 8
        for (int k = 0; k < BK; ++k) {
            float a = As[ty][kb + k];
            float4 w = ((const float4*)&Ws[k][0])[tx];
            acc.x = fmaf(a, w.x, acc.x);
            acc.y = fmaf(a, w.y, acc.y);
            acc.z = fmaf(a, w.z, acc.z);
            acc.w = fmaf(a, w.w, acc.w);
        }
    }
    int grow = row0 + ty;
    if (grow < N) ((float4*)(H + (long long)grow * F))[tx] = acc;
}

// ---------------- fused CSR aggregation + self-loop + bias (+ReLU) ----------------
// One wave (F>=64) or half-wave (F=32) per dst node; register accumulation.

template<int F, bool RELU>
__global__ __launch_bounds__(256) void agg_kernel(const float* __restrict__ h,
                                                  const int* __restrict__ rp,
                                                  const int* __restrict__ col,
                                                  const float* __restrict__ dinv,
                                                  const float* __restrict__ bias,
                                                  float* __restrict__ out, int N) {
    constexpr int LPN = (F >= 64) ? 64 : F;   // lanes per node
    constexpr int VEC = F / LPN;              // 128->2, 64->1, 32->1
    const int tid = threadIdx.x;
    const int lane = tid % LPN;
    const int node = blockIdx.x * (256 / LPN) + tid / LPN;
    if (node >= N) return;

    const int f0 = lane * VEC;
    const float self = dinv[node];
    float acc[VEC];
    const float* hp = h + (size_t)node * F + f0;
#pragma unroll
    for (int v = 0; v < VEC; ++v) acc[v] = hp[v] * self * self;  // self-loop term

    int e = rp[node];
    const int e1 = rp[node + 1];
    for (; e + 2 <= e1; e += 2) {
        int sA = col[e], sB = col[e + 1];
        float nA = dinv[sA] * self;
        float nB = dinv[sB] * self;
        const float* pA = h + (size_t)sA * F + f0;
        const float* pB = h + (size_t)sB * F + f0;
#pragma unroll
        for (int v = 0; v < VEC; ++v)
            acc[v] = fmaf(pA[v], nA, fmaf(pB[v], nB, acc[v]));
    }
    if (e < e1) {
        int sA = col[e];
        float nA = dinv[sA] * self;
        const float* pA = h + (size_t)sA * F + f0;
#pragma unroll
        for (int v = 0; v < VEC; ++v) acc[v] = fmaf(pA[v], nA, acc[v]);
    }

    float* op = out + (size_t)node * F + f0;
#pragma unroll
    for (int v = 0; v < VEC; ++v) {
        float r = acc[v] + bias[f0 + v];
        if (RELU) r = fmaxf(r, 0.f);
        op[v] = r;
    }
}

// ---------------- launcher ----------------

extern "C" void kernel_launch(void* const* d_in, const int* in_sizes, int n_in,
                              void* d_out, int out_size, void* d_ws, size_t ws_size,
                              hipStream_t stream) {
    const float* x  = (const float*)d_in[0];
    const int*   ei = (const int*)d_in[1];
    const float* W1 = (const float*)d_in[2];
    const float* b1 = (const float*)d_in[3];
    const float* W2 = (const float*)d_in[4];
    const float* b2 = (const float*)d_in[5];
    const float* W3 = (const float*)d_in[6];
    const float* b3 = (const float*)d_in[7];
    const float* W4 = (const float*)d_in[8];
    const float* b4 = (const float*)d_in[9];

    const int N = in_sizes[0] / 256;
    const int E = in_sizes[1] / 2;
    const int* src = ei;       // edge_index[0]
    const int* dst = ei + E;   // edge_index[1]

    const int NB = CDIV(N, 512);   // scan blocks (<=256 for N<=131072)

    // workspace layout (256B-aligned chunks)
    char* base = (char*)d_ws;
    size_t o = 0;
    auto alloc = [&](size_t bytes) { char* p = base + o; o += (bytes + 255) & ~(size_t)255; return p; };
    int*   cnt  = (int*)  alloc(sizeof(int) * N);        // histogram, then bucket-fill cursor
    int*   rp   = (int*)  alloc(sizeof(int) * (N + 1));  // CSR row pointers
    int*   aux  = (int*)  alloc(sizeof(int) * 256);      // scan block sums
    float* dinv = (float*)alloc(sizeof(float) * N);
    int*   col  = (int*)  alloc(sizeof(int) * E);        // CSR src indices
    float* bufA = (float*)alloc(sizeof(float) * (size_t)N * 128);
    float* bufB = (float*)alloc(sizeof(float) * (size_t)N * 128);
    float* out  = (float*)d_out;

    // --- CSR build + normalization ---
    zero_int_kernel<<<CDIV(N, 256), 256, 0, stream>>>(cnt, N);
    hist_kernel<<<CDIV(E, 256), 256, 0, stream>>>(dst, cnt, E);
    dinv_kernel<<<CDIV(N, 256), 256, 0, stream>>>(cnt, dinv, N);
    scan_block_kernel<<<NB, 512, 0, stream>>>(cnt, rp, aux, N);
    scan_aux_kernel<<<1, 256, 0, stream>>>(aux, NB);
    scan_add_kernel<<<CDIV(N + 1, 256), 256, 0, stream>>>(rp, aux, N, E);
    zero_int_kernel<<<CDIV(N, 256), 256, 0, stream>>>(cnt, N);
    fill_csr_kernel<<<CDIV(E, 256), 256, 0, stream>>>(src, dst, rp, cnt, col, E);

    // --- layer 1: x[N,256] @ W1 -> 128, agg, relu ---
    gemm_kernel<256, 128><<<CDIV(N, 8), 256, 0, stream>>>(x, W1, bufA, N);
    agg_kernel<128, true><<<CDIV(N, 4), 256, 0, stream>>>(bufA, rp, col, dinv, b1, bufB, N);

    // --- layer 2: [N,128] @ W2 -> 128, agg, relu ---
    gemm_kernel<128, 128><<<CDIV(N, 8), 256, 0, stream>>>(bufB, W2, bufA, N);
    agg_kernel<128, true><<<CDIV(N, 4), 256, 0, stream>>>(bufA, rp, col, dinv, b2, bufB, N);

    // --- layer 3: [N,128] @ W3 -> 64, agg, relu ---
    gemm_kernel<128, 64><<<CDIV(N, 16), 256, 0, stream>>>(bufB, W3, bufA, N);
    agg_kernel<64, true><<<CDIV(N, 4), 256, 0, stream>>>(bufA, rp, col, dinv, b3, bufB, N);

    // --- layer 4: [N,64] @ W4 -> 32, agg into d_out, no relu ---
    gemm_kernel<64, 32><<<CDIV(N, 32), 256, 0, stream>>>(bufB, W4, bufA, N);
    agg_kernel<32, false><<<CDIV(N, 8), 256, 0, stream>>>(bufA, rp, col, dinv, b4, out, N);
}

// Round 4
// 703.283 us; speedup vs baseline: 11.1981x; 1.2915x over previous
//
#include <hip/hip_runtime.h>

#define CDIV(a,b) (((a)+(b)-1)/(b))

typedef float f32x4 __attribute__((ext_vector_type(4)));
typedef short short8 __attribute__((ext_vector_type(8)));

// ---------------- bf16 helpers (RNE) ----------------

__device__ inline unsigned short rne_bf16(float f) {
    unsigned int u = __builtin_bit_cast(unsigned int, f);
    u += 0x7FFFu + ((u >> 16) & 1u);
    return (unsigned short)(u >> 16);
}

struct BF16Pair { short hi, lo; };

__device__ inline BF16Pair split_bf16(float f) {
    unsigned short h = rne_bf16(f);
    float fh = __builtin_bit_cast(float, (unsigned int)h << 16);
    BF16Pair p;
    p.hi = (short)h;
    p.lo = (short)rne_bf16(f - fh);
    return p;
}

// ---------------- CSR build: histogram, scan, bucket-fill ----------------

__global__ void zero_int_kernel(int* p, int n) {
    int i = blockIdx.x * blockDim.x + threadIdx.x;
    if (i < n) p[i] = 0;
}

__global__ void hist_kernel(const int* __restrict__ dst, int* cnt, int E) {
    int i = blockIdx.x * blockDim.x + threadIdx.x;
    if (i < E) atomicAdd(&cnt[dst[i]], 1);
}

__global__ void dinv_kernel(const int* __restrict__ cnt, float* dinv, int n) {
    int i = blockIdx.x * blockDim.x + threadIdx.x;
    if (i < n) dinv[i] = rsqrtf((float)cnt[i] + 1.0f);
}

__global__ __launch_bounds__(512) void scan_block_kernel(const int* __restrict__ cnt,
                                                         int* rp, int* aux, int N) {
    __shared__ int s[512];
    int t = threadIdx.x;
    int i = blockIdx.x * 512 + t;
    int v = (i < N) ? cnt[i] : 0;
    s[t] = v;
    __syncthreads();
    for (int off = 1; off < 512; off <<= 1) {
        int x = (t >= off) ? s[t - off] : 0;
        __syncthreads();
        s[t] += x;
        __syncthreads();
    }
    if (i < N) rp[i] = s[t] - v;
    if (t == 511) aux[blockIdx.x] = s[511];
}

__global__ __launch_bounds__(256) void scan_aux_kernel(int* aux, int nb) {
    __shared__ int s[256];
    int t = threadIdx.x;
    int v = (t < nb) ? aux[t] : 0;
    s[t] = v;
    __syncthreads();
    for (int off = 1; off < 256; off <<= 1) {
        int x = (t >= off) ? s[t - off] : 0;
        __syncthreads();
        s[t] += x;
        __syncthreads();
    }
    if (t < nb) aux[t] = s[t] - v;
}

__global__ void scan_add_kernel(int* rp, const int* __restrict__ aux, int N, int E) {
    int i = blockIdx.x * blockDim.x + threadIdx.x;
    if (i < N) rp[i] += aux[i >> 9];
    if (i == N) rp[N] = E;
}

__global__ void fill_csr_kernel(const int* __restrict__ src, const int* __restrict__ dst,
                                const int* __restrict__ rp, int* fill, int* col, int E) {
    int e = blockIdx.x * blockDim.x + threadIdx.x;
    if (e >= E) return;
    int d = dst[e];
    int pos = rp[d] + atomicAdd(&fill[d], 1);
    col[pos] = src[e];
}

// ---------------- W prep: fp32 [K][F] -> split-bf16 in MFMA B-fragment order ----
// flat idx = ((kb*CB + cb)*64 + lane)*8 + e  <->  W[kb*32 + (lane/16)*8 + e][cb*16 + lane%16]

template<int K, int F>
__global__ void wprep_kernel(const float* __restrict__ W, short* __restrict__ whi,
                             short* __restrict__ wlo) {
    constexpr int CB = F / 16;
    int idx = blockIdx.x * 256 + threadIdx.x;
    if (idx >= K * F) return;
    int e = idx & 7;
    int lane = (idx >> 3) & 63;
    int fc = idx >> 9;               // kb*CB + cb
    int kb = fc / CB, cb = fc % CB;
    int k = kb * 32 + (lane >> 4) * 8 + e;
    int colv = cb * 16 + (lane & 15);
    BF16Pair p = split_bf16(W[k * F + colv]);
    whi[idx] = p.hi;
    wlo[idx] = p.lo;
}

// ---------------- MFMA GEMM: H[N,F] = A[N,K] @ W[K,F], split-bf16, fp32 accum ----
// Per wave: 32 rows (2 row-frags) x F cols. No LDS: W fragments are L2-resident
// pre-swizzled streams, read as coalesced dwordx4.

template<int K, int F>
__global__ __launch_bounds__(256) void mfma_gemm(const float* __restrict__ A,
                                                 const short* __restrict__ Whi,
                                                 const short* __restrict__ Wlo,
                                                 float* __restrict__ H, int N) {
    constexpr int CB = F / 16;
    constexpr int KB = K / 32;
    constexpr int MT = 2;                 // row-frags per wave
    const int tid = threadIdx.x;
    const int wid = tid >> 6, lane = tid & 63;
    const int rowf = lane & 15;           // A row within fragment / D col within fragment
    const int kgrp = lane >> 4;           // k-group: k offset = kgrp*8
    const long long row0 = (long long)blockIdx.x * (MT * 16 * 4) + wid * (MT * 16);

    f32x4 acc[MT][CB] = {};

    for (int kb = 0; kb < KB; ++kb) {
        short8 ahi[MT], alo[MT];
#pragma unroll
        for (int mt = 0; mt < MT; ++mt) {
            long long r = row0 + mt * 16 + rowf;
            short8 h = {0,0,0,0,0,0,0,0}, l = {0,0,0,0,0,0,0,0};
            if (r < N) {
                const float* ap = A + (size_t)r * K + kb * 32 + kgrp * 8;
                float4 f0 = ((const float4*)ap)[0];
                float4 f1 = ((const float4*)ap)[1];
                float fv[8] = {f0.x, f0.y, f0.z, f0.w, f1.x, f1.y, f1.z, f1.w};
#pragma unroll
                for (int j = 0; j < 8; ++j) {
                    BF16Pair p = split_bf16(fv[j]);
                    h[j] = p.hi;
                    l[j] = p.lo;
                }
            }
            ahi[mt] = h;
            alo[mt] = l;
        }
#pragma unroll
        for (int cb = 0; cb < CB; ++cb) {
            size_t fo = ((size_t)(kb * CB + cb) * 64 + lane) * 8;
            short8 bhi = *(const short8*)(Whi + fo);
            short8 blo = *(const short8*)(Wlo + fo);
#pragma unroll
            for (int mt = 0; mt < MT; ++mt) {
                acc[mt][cb] = __builtin_amdgcn_mfma_f32_16x16x32_bf16(ahi[mt], bhi, acc[mt][cb], 0, 0, 0);
                acc[mt][cb] = __builtin_amdgcn_mfma_f32_16x16x32_bf16(alo[mt], bhi, acc[mt][cb], 0, 0, 0);
                acc[mt][cb] = __builtin_amdgcn_mfma_f32_16x16x32_bf16(ahi[mt], blo, acc[mt][cb], 0, 0, 0);
            }
        }
    }

    // D layout: col = lane&15, row = (lane>>4)*4 + j
    const int rsub = (lane >> 4) * 4;
#pragma unroll
    for (int mt = 0; mt < MT; ++mt) {
        long long rbase = row0 + mt * 16 + rsub;
#pragma unroll
        for (int cb = 0; cb < CB; ++cb) {
            int colv = cb * 16 + rowf;
#pragma unroll
            for (int j = 0; j < 4; ++j) {
                long long r = rbase + j;
                if (r < N) H[(size_t)r * F + colv] = acc[mt][cb][j];
            }
        }
    }
}

// ---------------- fused CSR aggregation + self-loop + bias (+ReLU) ----------------

template<int F, bool RELU>
__global__ __launch_bounds__(256) void agg_kernel(const float* __restrict__ h,
                                                  const int* __restrict__ rp,
                                                  const int* __restrict__ col,
                                                  const float* __restrict__ dinv,
                                                  const float* __restrict__ bias,
                                                  float* __restrict__ out, int N) {
    constexpr int LPN = (F >= 64) ? 64 : F;
    constexpr int VEC = F / LPN;
    const int tid = threadIdx.x;
    const int lane = tid % LPN;
    const int node = blockIdx.x * (256 / LPN) + tid / LPN;
    if (node >= N) return;

    const int f0 = lane * VEC;
    const float self = dinv[node];
    float acc[VEC];
    const float* hp = h + (size_t)node * F + f0;
#pragma unroll
    for (int v = 0; v < VEC; ++v) acc[v] = hp[v] * self * self;

    int e = rp[node];
    const int e1 = rp[node + 1];
    for (; e + 2 <= e1; e += 2) {
        int sA = col[e], sB = col[e + 1];
        float nA = dinv[sA] * self;
        float nB = dinv[sB] * self;
        const float* pA = h + (size_t)sA * F + f0;
        const float* pB = h + (size_t)sB * F + f0;
#pragma unroll
        for (int v = 0; v < VEC; ++v)
            acc[v] = fmaf(pA[v], nA, fmaf(pB[v], nB, acc[v]));
    }
    if (e < e1) {
        int sA = col[e];
        float nA = dinv[sA] * self;
        const float* pA = h + (size_t)sA * F + f0;
#pragma unroll
        for (int v = 0; v < VEC; ++v) acc[v] = fmaf(pA[v], nA, acc[v]);
    }

    float* op = out + (size_t)node * F + f0;
#pragma unroll
    for (int v = 0; v < VEC; ++v) {
        float r = acc[v] + bias[f0 + v];
        if (RELU) r = fmaxf(r, 0.f);
        op[v] = r;
    }
}

// ---------------- launcher ----------------

extern "C" void kernel_launch(void* const* d_in, const int* in_sizes, int n_in,
                              void* d_out, int out_size, void* d_ws, size_t ws_size,
                              hipStream_t stream) {
    const float* x  = (const float*)d_in[0];
    const int*   ei = (const int*)d_in[1];
    const float* W1 = (const float*)d_in[2];
    const float* b1 = (const float*)d_in[3];
    const float* W2 = (const float*)d_in[4];
    const float* b2 = (const float*)d_in[5];
    const float* W3 = (const float*)d_in[6];
    const float* b3 = (const float*)d_in[7];
    const float* W4 = (const float*)d_in[8];
    const float* b4 = (const float*)d_in[9];

    const int N = in_sizes[0] / 256;
    const int E = in_sizes[1] / 2;
    const int* src = ei;
    const int* dst = ei + E;

    const int NB = CDIV(N, 512);

    char* base = (char*)d_ws;
    size_t o = 0;
    auto alloc = [&](size_t bytes) { char* p = base + o; o += (bytes + 255) & ~(size_t)255; return p; };
    int*   cnt  = (int*)  alloc(sizeof(int) * N);
    int*   rp   = (int*)  alloc(sizeof(int) * (N + 1));
    int*   aux  = (int*)  alloc(sizeof(int) * 256);
    float* dinv = (float*)alloc(sizeof(float) * N);
    int*   col  = (int*)  alloc(sizeof(int) * E);
    short* w1h  = (short*)alloc(sizeof(short) * 256 * 128);
    short* w1l  = (short*)alloc(sizeof(short) * 256 * 128);
    short* w2h  = (short*)alloc(sizeof(short) * 128 * 128);
    short* w2l  = (short*)alloc(sizeof(short) * 128 * 128);
    short* w3h  = (short*)alloc(sizeof(short) * 128 * 64);
    short* w3l  = (short*)alloc(sizeof(short) * 128 * 64);
    short* w4h  = (short*)alloc(sizeof(short) * 64 * 32);
    short* w4l  = (short*)alloc(sizeof(short) * 64 * 32);
    float* bufA = (float*)alloc(sizeof(float) * (size_t)N * 128);  // h (GEMM out)
    float* bufB = (float*)alloc(sizeof(float) * (size_t)N * 128);  // z (agg out)
    float* out  = (float*)d_out;

    // --- weight prep (split-bf16, fragment-swizzled) ---
    wprep_kernel<256, 128><<<CDIV(256 * 128, 256), 256, 0, stream>>>(W1, w1h, w1l);
    wprep_kernel<128, 128><<<CDIV(128 * 128, 256), 256, 0, stream>>>(W2, w2h, w2l);
    wprep_kernel<128, 64><<<CDIV(128 * 64, 256), 256, 0, stream>>>(W3, w3h, w3l);
    wprep_kernel<64, 32><<<CDIV(64 * 32, 256), 256, 0, stream>>>(W4, w4h, w4l);

    // --- CSR build + normalization ---
    zero_int_kernel<<<CDIV(N, 256), 256, 0, stream>>>(cnt, N);
    hist_kernel<<<CDIV(E, 256), 256, 0, stream>>>(dst, cnt, E);
    dinv_kernel<<<CDIV(N, 256), 256, 0, stream>>>(cnt, dinv, N);
    scan_block_kernel<<<NB, 512, 0, stream>>>(cnt, rp, aux, N);
    scan_aux_kernel<<<1, 256, 0, stream>>>(aux, NB);
    scan_add_kernel<<<CDIV(N + 1, 256), 256, 0, stream>>>(rp, aux, N, E);
    zero_int_kernel<<<CDIV(N, 256), 256, 0, stream>>>(cnt, N);
    fill_csr_kernel<<<CDIV(E, 256), 256, 0, stream>>>(src, dst, rp, cnt, col, E);

    const int GG = CDIV(N, 128);  // gemm grid (128 rows/block)

    // --- layer 1 ---
    mfma_gemm<256, 128><<<GG, 256, 0, stream>>>(x, w1h, w1l, bufA, N);
    agg_kernel<128, true><<<CDIV(N, 4), 256, 0, stream>>>(bufA, rp, col, dinv, b1, bufB, N);

    // --- layer 2 ---
    mfma_gemm<128, 128><<<GG, 256, 0, stream>>>(bufB, w2h, w2l, bufA, N);
    agg_kernel<128, true><<<CDIV(N, 4), 256, 0, stream>>>(bufA, rp, col, dinv, b2, bufB, N);

    // --- layer 3 ---
    mfma_gemm<128, 64><<<GG, 256, 0, stream>>>(bufB, w3h, w3l, bufA, N);
    agg_kernel<64, true><<<CDIV(N, 4), 256, 0, stream>>>(bufA, rp, col, dinv, b3, bufB, N);

    // --- layer 4 ---
    mfma_gemm<64, 32><<<GG, 256, 0, stream>>>(bufB, w4h, w4l, bufA, N);
    agg_kernel<32, false><<<CDIV(N, 8), 256, 0, stream>>>(bufA, rp, col, dinv, b4, out, N);
}

// Round 5
// 678.884 us; speedup vs baseline: 11.6005x; 1.0359x over previous
//
#include <hip/hip_runtime.h>

#define CDIV(a,b) (((a)+(b)-1)/(b))

typedef float f32x4 __attribute__((ext_vector_type(4)));
typedef short short8 __attribute__((ext_vector_type(8)));

// ---------------- bf16 helpers (RNE) ----------------

__device__ inline unsigned short rne_bf16(float f) {
    unsigned int u = __builtin_bit_cast(unsigned int, f);
    u += 0x7FFFu + ((u >> 16) & 1u);
    return (unsigned short)(u >> 16);
}

struct BF16Pair { short hi, lo; };

__device__ inline BF16Pair split_bf16(float f) {
    unsigned short h = rne_bf16(f);
    float fh = __builtin_bit_cast(float, (unsigned int)h << 16);
    BF16Pair p;
    p.hi = (short)h;
    p.lo = (short)rne_bf16(f - fh);
    return p;
}

// ---------------- CSR build: histogram, scan, bucket-fill ----------------

__global__ void zero_int_kernel(int* p, int n) {
    int i = blockIdx.x * blockDim.x + threadIdx.x;
    if (i < n) p[i] = 0;
}

__global__ void hist_kernel(const int* __restrict__ dst, int* cnt, int E) {
    int i = blockIdx.x * blockDim.x + threadIdx.x;
    if (i < E) atomicAdd(&cnt[dst[i]], 1);
}

__global__ void dinv_kernel(const int* __restrict__ cnt, float* dinv, int n) {
    int i = blockIdx.x * blockDim.x + threadIdx.x;
    if (i < n) dinv[i] = rsqrtf((float)cnt[i] + 1.0f);
}

__global__ __launch_bounds__(512) void scan_block_kernel(const int* __restrict__ cnt,
                                                         int* rp, int* aux, int N) {
    __shared__ int s[512];
    int t = threadIdx.x;
    int i = blockIdx.x * 512 + t;
    int v = (i < N) ? cnt[i] : 0;
    s[t] = v;
    __syncthreads();
    for (int off = 1; off < 512; off <<= 1) {
        int x = (t >= off) ? s[t - off] : 0;
        __syncthreads();
        s[t] += x;
        __syncthreads();
    }
    if (i < N) rp[i] = s[t] - v;
    if (t == 511) aux[blockIdx.x] = s[511];
}

__global__ __launch_bounds__(256) void scan_aux_kernel(int* aux, int nb) {
    __shared__ int s[256];
    int t = threadIdx.x;
    int v = (t < nb) ? aux[t] : 0;
    s[t] = v;
    __syncthreads();
    for (int off = 1; off < 256; off <<= 1) {
        int x = (t >= off) ? s[t - off] : 0;
        __syncthreads();
        s[t] += x;
        __syncthreads();
    }
    if (t < nb) aux[t] = s[t] - v;
}

__global__ void scan_add_kernel(int* rp, const int* __restrict__ aux, int N, int E) {
    int i = blockIdx.x * blockDim.x + threadIdx.x;
    if (i < N) rp[i] += aux[i >> 9];
    if (i == N) rp[N] = E;
}

__global__ void fill_csr_kernel(const int* __restrict__ src, const int* __restrict__ dst,
                                const int* __restrict__ rp, int* fill, int* col, int E) {
    int e = blockIdx.x * blockDim.x + threadIdx.x;
    if (e >= E) return;
    int d = dst[e];
    int pos = rp[d] + atomicAdd(&fill[d], 1);
    col[pos] = src[e];
}

// ---------------- W prep: fp32 [K][F] -> split-bf16 in MFMA B-fragment order ----

template<int K, int F>
__global__ void wprep_kernel(const float* __restrict__ W, short* __restrict__ whi,
                             short* __restrict__ wlo) {
    constexpr int CB = F / 16;
    int idx = blockIdx.x * 256 + threadIdx.x;
    if (idx >= K * F) return;
    int e = idx & 7;
    int lane = (idx >> 3) & 63;
    int fc = idx >> 9;               // kb*CB + cb
    int kb = fc / CB, cb = fc % CB;
    int k = kb * 32 + (lane >> 4) * 8 + e;
    int colv = cb * 16 + (lane & 15);
    BF16Pair p = split_bf16(W[k * F + colv]);
    whi[idx] = p.hi;
    wlo[idx] = p.lo;
}

// ---------------- MFMA GEMM: H[N,F] = dinv[r] * (A[N,K] @ W[K,F]) ----------------
// split-bf16, fp32 accum; dinv pre-scale folded into epilogue.

template<int K, int F>
__global__ __launch_bounds__(256) void mfma_gemm(const float* __restrict__ A,
                                                 const short* __restrict__ Whi,
                                                 const short* __restrict__ Wlo,
                                                 const float* __restrict__ dinv,
                                                 float* __restrict__ H, int N) {
    constexpr int CB = F / 16;
    constexpr int KB = K / 32;
    constexpr int MT = 2;                 // row-frags per wave
    const int tid = threadIdx.x;
    const int wid = tid >> 6, lane = tid & 63;
    const int rowf = lane & 15;
    const int kgrp = lane >> 4;
    const long long row0 = (long long)blockIdx.x * (MT * 16 * 4) + wid * (MT * 16);

    f32x4 acc[MT][CB] = {};

    for (int kb = 0; kb < KB; ++kb) {
        short8 ahi[MT], alo[MT];
#pragma unroll
        for (int mt = 0; mt < MT; ++mt) {
            long long r = row0 + mt * 16 + rowf;
            short8 h = {0,0,0,0,0,0,0,0}, l = {0,0,0,0,0,0,0,0};
            if (r < N) {
                const float* ap = A + (size_t)r * K + kb * 32 + kgrp * 8;
                float4 f0 = ((const float4*)ap)[0];
                float4 f1 = ((const float4*)ap)[1];
                float fv[8] = {f0.x, f0.y, f0.z, f0.w, f1.x, f1.y, f1.z, f1.w};
#pragma unroll
                for (int j = 0; j < 8; ++j) {
                    BF16Pair p = split_bf16(fv[j]);
                    h[j] = p.hi;
                    l[j] = p.lo;
                }
            }
            ahi[mt] = h;
            alo[mt] = l;
        }
#pragma unroll
        for (int cb = 0; cb < CB; ++cb) {
            size_t fo = ((size_t)(kb * CB + cb) * 64 + lane) * 8;
            short8 bhi = *(const short8*)(Whi + fo);
            short8 blo = *(const short8*)(Wlo + fo);
#pragma unroll
            for (int mt = 0; mt < MT; ++mt) {
                acc[mt][cb] = __builtin_amdgcn_mfma_f32_16x16x32_bf16(ahi[mt], bhi, acc[mt][cb], 0, 0, 0);
                acc[mt][cb] = __builtin_amdgcn_mfma_f32_16x16x32_bf16(alo[mt], bhi, acc[mt][cb], 0, 0, 0);
                acc[mt][cb] = __builtin_amdgcn_mfma_f32_16x16x32_bf16(ahi[mt], blo, acc[mt][cb], 0, 0, 0);
            }
        }
    }

    // D layout: col = lane&15, row = (lane>>4)*4 + j ; scale row by dinv[row]
    const int rsub = (lane >> 4) * 4;
#pragma unroll
    for (int mt = 0; mt < MT; ++mt) {
        long long rbase = row0 + mt * 16 + rsub;
        float dv[4];
#pragma unroll
        for (int j = 0; j < 4; ++j) dv[j] = (rbase + j < N) ? dinv[rbase + j] : 0.f;
#pragma unroll
        for (int cb = 0; cb < CB; ++cb) {
            int colv = cb * 16 + rowf;
#pragma unroll
            for (int j = 0; j < 4; ++j) {
                long long r = rbase + j;
                if (r < N) H[(size_t)r * F + colv] = acc[mt][cb][j] * dv[j];
            }
        }
    }
}

// ---------------- fused CSR aggregation ----------------
// hs is pre-scaled: hs[r] = dinv[r] * h[r].
// z[d] = dinv[d] * (hs[d] + sum_{s in N(d)} hs[s]) + bias  (+ReLU)
// One wave (F>=64) or half-wave (F=32) per node; 4 gathers in flight.

template<int F, bool RELU>
__global__ __launch_bounds__(256) void agg_kernel(const float* __restrict__ hs,
                                                  const int* __restrict__ rp,
                                                  const int* __restrict__ col,
                                                  const float* __restrict__ dinv,
                                                  const float* __restrict__ bias,
                                                  float* __restrict__ out, int N) {
    constexpr int LPN = (F >= 64) ? 64 : F;
    constexpr int VEC = F / LPN;
    const int tid = threadIdx.x;
    const int lane = tid % LPN;
    const int node = blockIdx.x * (256 / LPN) + tid / LPN;
    if (node >= N) return;

    const int f0 = lane * VEC;
    float acc[VEC];
    const float* hp = hs + (size_t)node * F + f0;
#pragma unroll
    for (int v = 0; v < VEC; ++v) acc[v] = hp[v];   // self-loop term (pre-scaled)

    int e = rp[node];
    const int e1 = rp[node + 1];
    for (; e + 4 <= e1; e += 4) {
        int s0 = col[e], s1 = col[e + 1], s2 = col[e + 2], s3 = col[e + 3];
        const float* p0 = hs + (size_t)s0 * F + f0;
        const float* p1 = hs + (size_t)s1 * F + f0;
        const float* p2 = hs + (size_t)s2 * F + f0;
        const float* p3 = hs + (size_t)s3 * F + f0;
        float v0[VEC], v1[VEC], v2[VEC], v3[VEC];
#pragma unroll
        for (int v = 0; v < VEC; ++v) v0[v] = p0[v];
#pragma unroll
        for (int v = 0; v < VEC; ++v) v1[v] = p1[v];
#pragma unroll
        for (int v = 0; v < VEC; ++v) v2[v] = p2[v];
#pragma unroll
        for (int v = 0; v < VEC; ++v) v3[v] = p3[v];
#pragma unroll
        for (int v = 0; v < VEC; ++v) acc[v] += (v0[v] + v1[v]) + (v2[v] + v3[v]);
    }
    for (; e < e1; ++e) {
        const float* p0 = hs + (size_t)col[e] * F + f0;
#pragma unroll
        for (int v = 0; v < VEC; ++v) acc[v] += p0[v];
    }

    const float self = dinv[node];
    float* op = out + (size_t)node * F + f0;
#pragma unroll
    for (int v = 0; v < VEC; ++v) {
        float r = fmaf(acc[v], self, bias[f0 + v]);
        if (RELU) r = fmaxf(r, 0.f);
        op[v] = r;
    }
}

// ---------------- launcher ----------------

extern "C" void kernel_launch(void* const* d_in, const int* in_sizes, int n_in,
                              void* d_out, int out_size, void* d_ws, size_t ws_size,
                              hipStream_t stream) {
    const float* x  = (const float*)d_in[0];
    const int*   ei = (const int*)d_in[1];
    const float* W1 = (const float*)d_in[2];
    const float* b1 = (const float*)d_in[3];
    const float* W2 = (const float*)d_in[4];
    const float* b2 = (const float*)d_in[5];
    const float* W3 = (const float*)d_in[6];
    const float* b3 = (const float*)d_in[7];
    const float* W4 = (const float*)d_in[8];
    const float* b4 = (const float*)d_in[9];

    const int N = in_sizes[0] / 256;
    const int E = in_sizes[1] / 2;
    const int* src = ei;
    const int* dst = ei + E;

    const int NB = CDIV(N, 512);

    char* base = (char*)d_ws;
    size_t o = 0;
    auto alloc = [&](size_t bytes) { char* p = base + o; o += (bytes + 255) & ~(size_t)255; return p; };
    int*   cnt  = (int*)  alloc(sizeof(int) * N);
    int*   rp   = (int*)  alloc(sizeof(int) * (N + 1));
    int*   aux  = (int*)  alloc(sizeof(int) * 256);
    float* dinv = (float*)alloc(sizeof(float) * N);
    int*   col  = (int*)  alloc(sizeof(int) * E);
    short* w1h  = (short*)alloc(sizeof(short) * 256 * 128);
    short* w1l  = (short*)alloc(sizeof(short) * 256 * 128);
    short* w2h  = (short*)alloc(sizeof(short) * 128 * 128);
    short* w2l  = (short*)alloc(sizeof(short) * 128 * 128);
    short* w3h  = (short*)alloc(sizeof(short) * 128 * 64);
    short* w3l  = (short*)alloc(sizeof(short) * 128 * 64);
    short* w4h  = (short*)alloc(sizeof(short) * 64 * 32);
    short* w4l  = (short*)alloc(sizeof(short) * 64 * 32);
    float* bufA = (float*)alloc(sizeof(float) * (size_t)N * 128);  // hs (GEMM out, pre-scaled)
    float* bufB = (float*)alloc(sizeof(float) * (size_t)N * 128);  // z (agg out)
    float* out  = (float*)d_out;

    // --- weight prep (split-bf16, fragment-swizzled) ---
    wprep_kernel<256, 128><<<CDIV(256 * 128, 256), 256, 0, stream>>>(W1, w1h, w1l);
    wprep_kernel<128, 128><<<CDIV(128 * 128, 256), 256, 0, stream>>>(W2, w2h, w2l);
    wprep_kernel<128, 64><<<CDIV(128 * 64, 256), 256, 0, stream>>>(W3, w3h, w3l);
    wprep_kernel<64, 32><<<CDIV(64 * 32, 256), 256, 0, stream>>>(W4, w4h, w4l);

    // --- CSR build + normalization ---
    zero_int_kernel<<<CDIV(N, 256), 256, 0, stream>>>(cnt, N);
    hist_kernel<<<CDIV(E, 256), 256, 0, stream>>>(dst, cnt, E);
    dinv_kernel<<<CDIV(N, 256), 256, 0, stream>>>(cnt, dinv, N);
    scan_block_kernel<<<NB, 512, 0, stream>>>(cnt, rp, aux, N);
    scan_aux_kernel<<<1, 256, 0, stream>>>(aux, NB);
    scan_add_kernel<<<CDIV(N + 1, 256), 256, 0, stream>>>(rp, aux, N, E);
    zero_int_kernel<<<CDIV(N, 256), 256, 0, stream>>>(cnt, N);
    fill_csr_kernel<<<CDIV(E, 256), 256, 0, stream>>>(src, dst, rp, cnt, col, E);

    const int GG = CDIV(N, 128);  // gemm grid (128 rows/block)

    // --- layer 1 ---
    mfma_gemm<256, 128><<<GG, 256, 0, stream>>>(x, w1h, w1l, dinv, bufA, N);
    agg_kernel<128, true><<<CDIV(N, 4), 256, 0, stream>>>(bufA, rp, col, dinv, b1, bufB, N);

    // --- layer 2 ---
    mfma_gemm<128, 128><<<GG, 256, 0, stream>>>(bufB, w2h, w2l, dinv, bufA, N);
    agg_kernel<128, true><<<CDIV(N, 4), 256, 0, stream>>>(bufA, rp, col, dinv, b2, bufB, N);

    // --- layer 3 ---
    mfma_gemm<128, 64><<<GG, 256, 0, stream>>>(bufB, w3h, w3l, dinv, bufA, N);
    agg_kernel<64, true><<<CDIV(N, 4), 256, 0, stream>>>(bufA, rp, col, dinv, b3, bufB, N);

    // --- layer 4 ---
    mfma_gemm<64, 32><<<GG, 256, 0, stream>>>(bufB, w4h, w4l, dinv, bufA, N);
    agg_kernel<32, false><<<CDIV(N, 8), 256, 0, stream>>>(bufA, rp, col, dinv, b4, out, N);
}

// Round 6
// 659.291 us; speedup vs baseline: 11.9453x; 1.0297x over previous
//
#include <hip/hip_runtime.h>

#define CDIV(a,b) (((a)+(b)-1)/(b))

typedef float f32x4 __attribute__((ext_vector_type(4)));
typedef short short8 __attribute__((ext_vector_type(8)));

// ---------------- bf16 helpers (RNE) ----------------

__device__ inline unsigned short rne_bf16(float f) {
    unsigned int u = __builtin_bit_cast(unsigned int, f);
    u += 0x7FFFu + ((u >> 16) & 1u);
    return (unsigned short)(u >> 16);
}

struct BF16Pair { short hi, lo; };

__device__ inline BF16Pair split_bf16(float f) {
    unsigned short h = rne_bf16(f);
    float fh = __builtin_bit_cast(float, (unsigned int)h << 16);
    BF16Pair p;
    p.hi = (short)h;
    p.lo = (short)rne_bf16(f - fh);
    return p;
}

// ---------------- CSR build: histogram, scan, bucket-fill ----------------

__global__ void zero_int_kernel(int* p, int n) {
    int i = blockIdx.x * blockDim.x + threadIdx.x;
    if (i < n) p[i] = 0;
}

__global__ void hist_kernel(const int* __restrict__ dst, int* cnt, int E) {
    int i = blockIdx.x * blockDim.x + threadIdx.x;
    if (i < E) atomicAdd(&cnt[dst[i]], 1);
}

__global__ void dinv_kernel(const int* __restrict__ cnt, float* dinv, int n) {
    int i = blockIdx.x * blockDim.x + threadIdx.x;
    if (i < n) dinv[i] = rsqrtf((float)cnt[i] + 1.0f);
}

__global__ __launch_bounds__(512) void scan_block_kernel(const int* __restrict__ cnt,
                                                         int* rp, int* aux, int N) {
    __shared__ int s[512];
    int t = threadIdx.x;
    int i = blockIdx.x * 512 + t;
    int v = (i < N) ? cnt[i] : 0;
    s[t] = v;
    __syncthreads();
    for (int off = 1; off < 512; off <<= 1) {
        int x = (t >= off) ? s[t - off] : 0;
        __syncthreads();
        s[t] += x;
        __syncthreads();
    }
    if (i < N) rp[i] = s[t] - v;
    if (t == 511) aux[blockIdx.x] = s[511];
}

__global__ __launch_bounds__(256) void scan_aux_kernel(int* aux, int nb) {
    __shared__ int s[256];
    int t = threadIdx.x;
    int v = (t < nb) ? aux[t] : 0;
    s[t] = v;
    __syncthreads();
    for (int off = 1; off < 256; off <<= 1) {
        int x = (t >= off) ? s[t - off] : 0;
        __syncthreads();
        s[t] += x;
        __syncthreads();
    }
    if (t < nb) aux[t] = s[t] - v;
}

__global__ void scan_add_kernel(int* rp, const int* __restrict__ aux, int N, int E) {
    int i = blockIdx.x * blockDim.x + threadIdx.x;
    if (i < N) rp[i] += aux[i >> 9];
    if (i == N) rp[N] = E;
}

__global__ void fill_csr_kernel(const int* __restrict__ src, const int* __restrict__ dst,
                                const int* __restrict__ rp, int* fill, int* col, int E) {
    int e = blockIdx.x * blockDim.x + threadIdx.x;
    if (e >= E) return;
    int d = dst[e];
    int pos = rp[d] + atomicAdd(&fill[d], 1);
    col[pos] = src[e];
}

// ---------------- W prep: fp32 [K][F] -> split-bf16 in MFMA B-fragment order ----

template<int K, int F>
__global__ void wprep_kernel(const float* __restrict__ W, short* __restrict__ whi,
                             short* __restrict__ wlo) {
    constexpr int CB = F / 16;
    int idx = blockIdx.x * 256 + threadIdx.x;
    if (idx >= K * F) return;
    int e = idx & 7;
    int lane = (idx >> 3) & 63;
    int fc = idx >> 9;               // kb*CB + cb
    int kb = fc / CB, cb = fc % CB;
    int k = kb * 32 + (lane >> 4) * 8 + e;
    int colv = cb * 16 + (lane & 15);
    BF16Pair p = split_bf16(W[k * F + colv]);
    whi[idx] = p.hi;
    wlo[idx] = p.lo;
}

// ---------------- MFMA GEMM: H[N,F] = dinv[r] * (A[N,K] @ W[K,F]) ----------------

template<int K, int F>
__global__ __launch_bounds__(256) void mfma_gemm(const float* __restrict__ A,
                                                 const short* __restrict__ Whi,
                                                 const short* __restrict__ Wlo,
                                                 const float* __restrict__ dinv,
                                                 float* __restrict__ H, int N) {
    constexpr int CB = F / 16;
    constexpr int KB = K / 32;
    constexpr int MT = 2;                 // row-frags per wave
    const int tid = threadIdx.x;
    const int wid = tid >> 6, lane = tid & 63;
    const int rowf = lane & 15;
    const int kgrp = lane >> 4;
    const long long row0 = (long long)blockIdx.x * (MT * 16 * 4) + wid * (MT * 16);

    f32x4 acc[MT][CB] = {};

    for (int kb = 0; kb < KB; ++kb) {
        short8 ahi[MT], alo[MT];
#pragma unroll
        for (int mt = 0; mt < MT; ++mt) {
            long long r = row0 + mt * 16 + rowf;
            short8 h = {0,0,0,0,0,0,0,0}, l = {0,0,0,0,0,0,0,0};
            if (r < N) {
                const float* ap = A + (size_t)r * K + kb * 32 + kgrp * 8;
                float4 f0 = ((const float4*)ap)[0];
                float4 f1 = ((const float4*)ap)[1];
                float fv[8] = {f0.x, f0.y, f0.z, f0.w, f1.x, f1.y, f1.z, f1.w};
#pragma unroll
                for (int j = 0; j < 8; ++j) {
                    BF16Pair p = split_bf16(fv[j]);
                    h[j] = p.hi;
                    l[j] = p.lo;
                }
            }
            ahi[mt] = h;
            alo[mt] = l;
        }
#pragma unroll
        for (int cb = 0; cb < CB; ++cb) {
            size_t fo = ((size_t)(kb * CB + cb) * 64 + lane) * 8;
            short8 bhi = *(const short8*)(Whi + fo);
            short8 blo = *(const short8*)(Wlo + fo);
#pragma unroll
            for (int mt = 0; mt < MT; ++mt) {
                acc[mt][cb] = __builtin_amdgcn_mfma_f32_16x16x32_bf16(ahi[mt], bhi, acc[mt][cb], 0, 0, 0);
                acc[mt][cb] = __builtin_amdgcn_mfma_f32_16x16x32_bf16(alo[mt], bhi, acc[mt][cb], 0, 0, 0);
                acc[mt][cb] = __builtin_amdgcn_mfma_f32_16x16x32_bf16(ahi[mt], blo, acc[mt][cb], 0, 0, 0);
            }
        }
    }

    // D layout: col = lane&15, row = (lane>>4)*4 + j ; scale row by dinv[row]
    const int rsub = (lane >> 4) * 4;
#pragma unroll
    for (int mt = 0; mt < MT; ++mt) {
        long long rbase = row0 + mt * 16 + rsub;
        float dv[4];
#pragma unroll
        for (int j = 0; j < 4; ++j) dv[j] = (rbase + j < N) ? dinv[rbase + j] : 0.f;
#pragma unroll
        for (int cb = 0; cb < CB; ++cb) {
            int colv = cb * 16 + rowf;
#pragma unroll
            for (int j = 0; j < 4; ++j) {
                long long r = rbase + j;
                if (r < N) H[(size_t)r * F + colv] = acc[mt][cb][j] * dv[j];
            }
        }
    }
}

// ---------------- fused CSR aggregation ----------------
// hs is pre-scaled: hs[r] = dinv[r] * h[r].
// z[d] = dinv[d] * (hs[d] + sum_{s in N(d)} hs[s]) + bias  (+ReLU)
// LPN = F/4 lanes per node (16B/lane dwordx4 gathers); multiple nodes per wave
// -> each gather instruction moves (64/LPN) independent rows = 1KB/wave.

template<int F, bool RELU>
__global__ __launch_bounds__(256) void agg_kernel(const float* __restrict__ hs,
                                                  const int* __restrict__ rp,
                                                  const int* __restrict__ col,
                                                  const float* __restrict__ dinv,
                                                  const float* __restrict__ bias,
                                                  float* __restrict__ out, int N) {
    constexpr int LPN = F / 4;            // 128->32, 64->16, 32->8 lanes per node
    constexpr int NPB = 256 / LPN;        // nodes per block
    const int tid = threadIdx.x;
    const int lane = tid % LPN;
    const int node = blockIdx.x * NPB + tid / LPN;
    if (node >= N) return;

    const int f0 = lane * 4;
    const float* hbase = hs + f0;
    f32x4 acc = *(const f32x4*)(hbase + (size_t)node * F);   // self-loop (pre-scaled)

    int e = rp[node];
    const int e1 = rp[node + 1];
    for (; e + 4 <= e1; e += 4) {
        int s0 = col[e], s1 = col[e + 1], s2 = col[e + 2], s3 = col[e + 3];
        f32x4 v0 = *(const f32x4*)(hbase + (size_t)s0 * F);
        f32x4 v1 = *(const f32x4*)(hbase + (size_t)s1 * F);
        f32x4 v2 = *(const f32x4*)(hbase + (size_t)s2 * F);
        f32x4 v3 = *(const f32x4*)(hbase + (size_t)s3 * F);
        acc += (v0 + v1) + (v2 + v3);
    }
    for (; e < e1; ++e) {
        f32x4 v = *(const f32x4*)(hbase + (size_t)col[e] * F);
        acc += v;
    }

    const float self = dinv[node];
    f32x4 b = *(const f32x4*)(bias + f0);
    f32x4 r;
#pragma unroll
    for (int v = 0; v < 4; ++v) {
        float t = fmaf(acc[v], self, b[v]);
        if (RELU) t = fmaxf(t, 0.f);
        r[v] = t;
    }
    *(f32x4*)(out + (size_t)node * F + f0) = r;
}

// ---------------- launcher ----------------

extern "C" void kernel_launch(void* const* d_in, const int* in_sizes, int n_in,
                              void* d_out, int out_size, void* d_ws, size_t ws_size,
                              hipStream_t stream) {
    const float* x  = (const float*)d_in[0];
    const int*   ei = (const int*)d_in[1];
    const float* W1 = (const float*)d_in[2];
    const float* b1 = (const float*)d_in[3];
    const float* W2 = (const float*)d_in[4];
    const float* b2 = (const float*)d_in[5];
    const float* W3 = (const float*)d_in[6];
    const float* b3 = (const float*)d_in[7];
    const float* W4 = (const float*)d_in[8];
    const float* b4 = (const float*)d_in[9];

    const int N = in_sizes[0] / 256;
    const int E = in_sizes[1] / 2;
    const int* src = ei;
    const int* dst = ei + E;

    const int NB = CDIV(N, 512);

    char* base = (char*)d_ws;
    size_t o = 0;
    auto alloc = [&](size_t bytes) { char* p = base + o; o += (bytes + 255) & ~(size_t)255; return p; };
    int*   cnt  = (int*)  alloc(sizeof(int) * N);
    int*   rp   = (int*)  alloc(sizeof(int) * (N + 1));
    int*   aux  = (int*)  alloc(sizeof(int) * 256);
    float* dinv = (float*)alloc(sizeof(float) * N);
    int*   col  = (int*)  alloc(sizeof(int) * E);
    short* w1h  = (short*)alloc(sizeof(short) * 256 * 128);
    short* w1l  = (short*)alloc(sizeof(short) * 256 * 128);
    short* w2h  = (short*)alloc(sizeof(short) * 128 * 128);
    short* w2l  = (short*)alloc(sizeof(short) * 128 * 128);
    short* w3h  = (short*)alloc(sizeof(short) * 128 * 64);
    short* w3l  = (short*)alloc(sizeof(short) * 128 * 64);
    short* w4h  = (short*)alloc(sizeof(short) * 64 * 32);
    short* w4l  = (short*)alloc(sizeof(short) * 64 * 32);
    float* bufA = (float*)alloc(sizeof(float) * (size_t)N * 128);  // hs (GEMM out, pre-scaled)
    float* bufB = (float*)alloc(sizeof(float) * (size_t)N * 128);  // z (agg out)
    float* out  = (float*)d_out;

    // --- weight prep (split-bf16, fragment-swizzled) ---
    wprep_kernel<256, 128><<<CDIV(256 * 128, 256), 256, 0, stream>>>(W1, w1h, w1l);
    wprep_kernel<128, 128><<<CDIV(128 * 128, 256), 256, 0, stream>>>(W2, w2h, w2l);
    wprep_kernel<128, 64><<<CDIV(128 * 64, 256), 256, 0, stream>>>(W3, w3h, w3l);
    wprep_kernel<64, 32><<<CDIV(64 * 32, 256), 256, 0, stream>>>(W4, w4h, w4l);

    // --- CSR build + normalization ---
    zero_int_kernel<<<CDIV(N, 256), 256, 0, stream>>>(cnt, N);
    hist_kernel<<<CDIV(E, 256), 256, 0, stream>>>(dst, cnt, E);
    dinv_kernel<<<CDIV(N, 256), 256, 0, stream>>>(cnt, dinv, N);
    scan_block_kernel<<<NB, 512, 0, stream>>>(cnt, rp, aux, N);
    scan_aux_kernel<<<1, 256, 0, stream>>>(aux, NB);
    scan_add_kernel<<<CDIV(N + 1, 256), 256, 0, stream>>>(rp, aux, N, E);
    zero_int_kernel<<<CDIV(N, 256), 256, 0, stream>>>(cnt, N);
    fill_csr_kernel<<<CDIV(E, 256), 256, 0, stream>>>(src, dst, rp, cnt, col, E);

    const int GG = CDIV(N, 128);  // gemm grid (128 rows/block)

    // --- layer 1 ---
    mfma_gemm<256, 128><<<GG, 256, 0, stream>>>(x, w1h, w1l, dinv, bufA, N);
    agg_kernel<128, true><<<CDIV(N, 8), 256, 0, stream>>>(bufA, rp, col, dinv, b1, bufB, N);

    // --- layer 2 ---
    mfma_gemm<128, 128><<<GG, 256, 0, stream>>>(bufB, w2h, w2l, dinv, bufA, N);
    agg_kernel<128, true><<<CDIV(N, 8), 256, 0, stream>>>(bufA, rp, col, dinv, b2, bufB, N);

    // --- layer 3 ---
    mfma_gemm<128, 64><<<GG, 256, 0, stream>>>(bufB, w3h, w3l, dinv, bufA, N);
    agg_kernel<64, true><<<CDIV(N, 16), 256, 0, stream>>>(bufA, rp, col, dinv, b3, bufB, N);

    // --- layer 4 ---
    mfma_gemm<64, 32><<<GG, 256, 0, stream>>>(bufB, w4h, w4l, dinv, bufA, N);
    agg_kernel<32, false><<<CDIV(N, 32), 256, 0, stream>>>(bufA, rp, col, dinv, b4, out, N);
}

// Round 7
// 534.388 us; speedup vs baseline: 14.7373x; 1.2337x over previous
//
#include <hip/hip_runtime.h>

#define CDIV(a,b) (((a)+(b)-1)/(b))

typedef float f32x4 __attribute__((ext_vector_type(4)));
typedef short short8 __attribute__((ext_vector_type(8)));
typedef _Float16 h16x8 __attribute__((ext_vector_type(8)));

// ---------------- bf16 helpers (RNE) ----------------

__device__ inline unsigned short rne_bf16(float f) {
    unsigned int u = __builtin_bit_cast(unsigned int, f);
    u += 0x7FFFu + ((u >> 16) & 1u);
    return (unsigned short)(u >> 16);
}

struct BF16Pair { short hi, lo; };

__device__ inline BF16Pair split_bf16(float f) {
    unsigned short h = rne_bf16(f);
    float fh = __builtin_bit_cast(float, (unsigned int)h << 16);
    BF16Pair p;
    p.hi = (short)h;
    p.lo = (short)rne_bf16(f - fh);
    return p;
}

// ---------------- CSR build: histogram, scan, bucket-fill ----------------

__global__ void zero_int_kernel(int* p, int n) {
    int i = blockIdx.x * blockDim.x + threadIdx.x;
    if (i < n) p[i] = 0;
}

// 4 edges/thread, 4 independent fire-and-forget atomics in flight
__global__ void hist_kernel(const int* __restrict__ dst, int* cnt, int E) {
    int g = blockIdx.x * blockDim.x + threadIdx.x;
    int e0 = g * 4;
    if (e0 + 4 <= E) {
        int4 d4 = *(const int4*)(dst + e0);
        atomicAdd(&cnt[d4.x], 1);
        atomicAdd(&cnt[d4.y], 1);
        atomicAdd(&cnt[d4.z], 1);
        atomicAdd(&cnt[d4.w], 1);
    } else {
        for (int e = e0; e < E; ++e) atomicAdd(&cnt[dst[e]], 1);
    }
}

__global__ void dinv_kernel(const int* __restrict__ cnt, float* dinv, int n) {
    int i = blockIdx.x * blockDim.x + threadIdx.x;
    if (i < n) dinv[i] = rsqrtf((float)cnt[i] + 1.0f);
}

__global__ __launch_bounds__(512) void scan_block_kernel(const int* __restrict__ cnt,
                                                         int* rp, int* aux, int N) {
    __shared__ int s[512];
    int t = threadIdx.x;
    int i = blockIdx.x * 512 + t;
    int v = (i < N) ? cnt[i] : 0;
    s[t] = v;
    __syncthreads();
    for (int off = 1; off < 512; off <<= 1) {
        int x = (t >= off) ? s[t - off] : 0;
        __syncthreads();
        s[t] += x;
        __syncthreads();
    }
    if (i < N) rp[i] = s[t] - v;
    if (t == 511) aux[blockIdx.x] = s[511];
}

__global__ __launch_bounds__(256) void scan_aux_kernel(int* aux, int nb) {
    __shared__ int s[256];
    int t = threadIdx.x;
    int v = (t < nb) ? aux[t] : 0;
    s[t] = v;
    __syncthreads();
    for (int off = 1; off < 256; off <<= 1) {
        int x = (t >= off) ? s[t - off] : 0;
        __syncthreads();
        s[t] += x;
        __syncthreads();
    }
    if (t < nb) aux[t] = s[t] - v;
}

__global__ void scan_add_kernel(int* rp, const int* __restrict__ aux, int N, int E) {
    int i = blockIdx.x * blockDim.x + threadIdx.x;
    if (i < N) rp[i] += aux[i >> 9];
    if (i == N) rp[N] = E;
}

// cursor init: fill[i] = rp[i]  (removes rp load from fill_csr's dependent chain)
__global__ void copy_int_kernel(const int* __restrict__ rp, int* fill, int n) {
    int i = blockIdx.x * blockDim.x + threadIdx.x;
    if (i < n) fill[i] = rp[i];
}

// 4 edges/thread: 4 independent atomic RMW chains in flight
__global__ void fill_csr_kernel(const int* __restrict__ src, const int* __restrict__ dst,
                                int* fill, int* col, int E) {
    int g = blockIdx.x * blockDim.x + threadIdx.x;
    int e0 = g * 4;
    if (e0 + 4 <= E) {
        int4 d4 = *(const int4*)(dst + e0);
        int4 s4 = *(const int4*)(src + e0);
        int p0 = atomicAdd(&fill[d4.x], 1);
        int p1 = atomicAdd(&fill[d4.y], 1);
        int p2 = atomicAdd(&fill[d4.z], 1);
        int p3 = atomicAdd(&fill[d4.w], 1);
        col[p0] = s4.x;
        col[p1] = s4.y;
        col[p2] = s4.z;
        col[p3] = s4.w;
    } else {
        for (int e = e0; e < E; ++e) {
            int pos = atomicAdd(&fill[dst[e]], 1);
            col[pos] = src[e];
        }
    }
}

// ---------------- W prep: fp32 [K][F] -> split-bf16 in MFMA B-fragment order ----

template<int K, int F>
__global__ void wprep_kernel(const float* __restrict__ W, short* __restrict__ whi,
                             short* __restrict__ wlo) {
    constexpr int CB = F / 16;
    int idx = blockIdx.x * 256 + threadIdx.x;
    if (idx >= K * F) return;
    int e = idx & 7;
    int lane = (idx >> 3) & 63;
    int fc = idx >> 9;               // kb*CB + cb
    int kb = fc / CB, cb = fc % CB;
    int k = kb * 32 + (lane >> 4) * 8 + e;
    int colv = cb * 16 + (lane & 15);
    BF16Pair p = split_bf16(W[k * F + colv]);
    whi[idx] = p.hi;
    wlo[idx] = p.lo;
}

// ---------------- MFMA GEMM: H[N,F] = fp16( dinv[r] * (A[N,K] @ W[K,F]) ) --------

template<int K, int F>
__global__ __launch_bounds__(256) void mfma_gemm(const float* __restrict__ A,
                                                 const short* __restrict__ Whi,
                                                 const short* __restrict__ Wlo,
                                                 const float* __restrict__ dinv,
                                                 _Float16* __restrict__ H, int N) {
    constexpr int CB = F / 16;
    constexpr int KB = K / 32;
    constexpr int MT = 2;                 // row-frags per wave
    const int tid = threadIdx.x;
    const int wid = tid >> 6, lane = tid & 63;
    const int rowf = lane & 15;
    const int kgrp = lane >> 4;
    const long long row0 = (long long)blockIdx.x * (MT * 16 * 4) + wid * (MT * 16);

    f32x4 acc[MT][CB] = {};

    for (int kb = 0; kb < KB; ++kb) {
        short8 ahi[MT], alo[MT];
#pragma unroll
        for (int mt = 0; mt < MT; ++mt) {
            long long r = row0 + mt * 16 + rowf;
            short8 h = {0,0,0,0,0,0,0,0}, l = {0,0,0,0,0,0,0,0};
            if (r < N) {
                const float* ap = A + (size_t)r * K + kb * 32 + kgrp * 8;
                float4 f0 = ((const float4*)ap)[0];
                float4 f1 = ((const float4*)ap)[1];
                float fv[8] = {f0.x, f0.y, f0.z, f0.w, f1.x, f1.y, f1.z, f1.w};
#pragma unroll
                for (int j = 0; j < 8; ++j) {
                    BF16Pair p = split_bf16(fv[j]);
                    h[j] = p.hi;
                    l[j] = p.lo;
                }
            }
            ahi[mt] = h;
            alo[mt] = l;
        }
#pragma unroll
        for (int cb = 0; cb < CB; ++cb) {
            size_t fo = ((size_t)(kb * CB + cb) * 64 + lane) * 8;
            short8 bhi = *(const short8*)(Whi + fo);
            short8 blo = *(const short8*)(Wlo + fo);
#pragma unroll
            for (int mt = 0; mt < MT; ++mt) {
                acc[mt][cb] = __builtin_amdgcn_mfma_f32_16x16x32_bf16(ahi[mt], bhi, acc[mt][cb], 0, 0, 0);
                acc[mt][cb] = __builtin_amdgcn_mfma_f32_16x16x32_bf16(alo[mt], bhi, acc[mt][cb], 0, 0, 0);
                acc[mt][cb] = __builtin_amdgcn_mfma_f32_16x16x32_bf16(ahi[mt], blo, acc[mt][cb], 0, 0, 0);
            }
        }
    }

    // D layout: col = lane&15, row = (lane>>4)*4 + j ; scale row by dinv[row], cvt fp16
    const int rsub = (lane >> 4) * 4;
#pragma unroll
    for (int mt = 0; mt < MT; ++mt) {
        long long rbase = row0 + mt * 16 + rsub;
        float dv[4];
#pragma unroll
        for (int j = 0; j < 4; ++j) dv[j] = (rbase + j < N) ? dinv[rbase + j] : 0.f;
#pragma unroll
        for (int cb = 0; cb < CB; ++cb) {
            int colv = cb * 16 + rowf;
#pragma unroll
            for (int j = 0; j < 4; ++j) {
                long long r = rbase + j;
                if (r < N) H[(size_t)r * F + colv] = (_Float16)(acc[mt][cb][j] * dv[j]);
            }
        }
    }
}

// ---------------- fused CSR aggregation (fp16 gather, fp32 accum) ----------------
// hs[r] = fp16(dinv[r] * h[r]).
// z[d] = dinv[d] * (hs[d] + sum_{s in N(d)} hs[s]) + bias  (+ReLU)
// LPN = F/8 lanes per node, 16B (8 halfs) per lane -> one load instruction
// covers 64/LPN independent rows (F=128: 4 rows/instr, 1KB/wave).

template<int F, bool RELU>
__global__ __launch_bounds__(256) void agg_kernel(const _Float16* __restrict__ hs,
                                                  const int* __restrict__ rp,
                                                  const int* __restrict__ col,
                                                  const float* __restrict__ dinv,
                                                  const float* __restrict__ bias,
                                                  float* __restrict__ out, int N) {
    constexpr int LPN = F / 8;            // 128->16, 64->8, 32->4 lanes per node
    constexpr int NPB = 256 / LPN;        // nodes per block
    const int tid = threadIdx.x;
    const int lane = tid % LPN;
    const int node = blockIdx.x * NPB + tid / LPN;
    if (node >= N) return;

    const int f0 = lane * 8;
    const _Float16* hbase = hs + f0;

    float acc[8];
    {
        h16x8 sv = *(const h16x8*)(hbase + (size_t)node * F);   // self-loop (pre-scaled)
#pragma unroll
        for (int v = 0; v < 8; ++v) acc[v] = (float)sv[v];
    }

    int e = rp[node];
    const int e1 = rp[node + 1];
    for (; e + 4 <= e1; e += 4) {
        int s0 = col[e], s1 = col[e + 1], s2 = col[e + 2], s3 = col[e + 3];
        h16x8 v0 = *(const h16x8*)(hbase + (size_t)s0 * F);
        h16x8 v1 = *(const h16x8*)(hbase + (size_t)s1 * F);
        h16x8 v2 = *(const h16x8*)(hbase + (size_t)s2 * F);
        h16x8 v3 = *(const h16x8*)(hbase + (size_t)s3 * F);
#pragma unroll
        for (int v = 0; v < 8; ++v)
            acc[v] += ((float)v0[v] + (float)v1[v]) + ((float)v2[v] + (float)v3[v]);
    }
    for (; e < e1; ++e) {
        h16x8 v0 = *(const h16x8*)(hbase + (size_t)col[e] * F);
#pragma unroll
        for (int v = 0; v < 8; ++v) acc[v] += (float)v0[v];
    }

    const float self = dinv[node];
    float* op = out + (size_t)node * F + f0;
    const float* bp = bias + f0;
#pragma unroll
    for (int v = 0; v < 8; ++v) {
        float r = fmaf(acc[v], self, bp[v]);
        if (RELU) r = fmaxf(r, 0.f);
        op[v] = r;
    }
}

// ---------------- launcher ----------------

extern "C" void kernel_launch(void* const* d_in, const int* in_sizes, int n_in,
                              void* d_out, int out_size, void* d_ws, size_t ws_size,
                              hipStream_t stream) {
    const float* x  = (const float*)d_in[0];
    const int*   ei = (const int*)d_in[1];
    const float* W1 = (const float*)d_in[2];
    const float* b1 = (const float*)d_in[3];
    const float* W2 = (const float*)d_in[4];
    const float* b2 = (const float*)d_in[5];
    const float* W3 = (const float*)d_in[6];
    const float* b3 = (const float*)d_in[7];
    const float* W4 = (const float*)d_in[8];
    const float* b4 = (const float*)d_in[9];

    const int N = in_sizes[0] / 256;
    const int E = in_sizes[1] / 2;
    const int* src = ei;
    const int* dst = ei + E;

    const int NB = CDIV(N, 512);

    char* base = (char*)d_ws;
    size_t o = 0;
    auto alloc = [&](size_t bytes) { char* p = base + o; o += (bytes + 255) & ~(size_t)255; return p; };
    int*   cnt  = (int*)  alloc(sizeof(int) * N);        // histogram, then bucket cursor
    int*   rp   = (int*)  alloc(sizeof(int) * (N + 1));
    int*   aux  = (int*)  alloc(sizeof(int) * 256);
    float* dinv = (float*)alloc(sizeof(float) * N);
    int*   col  = (int*)  alloc(sizeof(int) * E);
    short* w1h  = (short*)alloc(sizeof(short) * 256 * 128);
    short* w1l  = (short*)alloc(sizeof(short) * 256 * 128);
    short* w2h  = (short*)alloc(sizeof(short) * 128 * 128);
    short* w2l  = (short*)alloc(sizeof(short) * 128 * 128);
    short* w3h  = (short*)alloc(sizeof(short) * 128 * 64);
    short* w3l  = (short*)alloc(sizeof(short) * 128 * 64);
    short* w4h  = (short*)alloc(sizeof(short) * 64 * 32);
    short* w4l  = (short*)alloc(sizeof(short) * 64 * 32);
    _Float16* hsbuf = (_Float16*)alloc(sizeof(_Float16) * (size_t)N * 128);  // GEMM out (pre-scaled, fp16)
    float*    zbuf  = (float*)   alloc(sizeof(float)    * (size_t)N * 128);  // agg out (fp32)
    float* out  = (float*)d_out;

    // --- weight prep (split-bf16, fragment-swizzled) ---
    wprep_kernel<256, 128><<<CDIV(256 * 128, 256), 256, 0, stream>>>(W1, w1h, w1l);
    wprep_kernel<128, 128><<<CDIV(128 * 128, 256), 256, 0, stream>>>(W2, w2h, w2l);
    wprep_kernel<128, 64><<<CDIV(128 * 64, 256), 256, 0, stream>>>(W3, w3h, w3l);
    wprep_kernel<64, 32><<<CDIV(64 * 32, 256), 256, 0, stream>>>(W4, w4h, w4l);

    // --- CSR build + normalization ---
    zero_int_kernel<<<CDIV(N, 256), 256, 0, stream>>>(cnt, N);
    hist_kernel<<<CDIV(E, 1024), 256, 0, stream>>>(dst, cnt, E);
    dinv_kernel<<<CDIV(N, 256), 256, 0, stream>>>(cnt, dinv, N);
    scan_block_kernel<<<NB, 512, 0, stream>>>(cnt, rp, aux, N);
    scan_aux_kernel<<<1, 256, 0, stream>>>(aux, NB);
    scan_add_kernel<<<CDIV(N + 1, 256), 256, 0, stream>>>(rp, aux, N, E);
    copy_int_kernel<<<CDIV(N, 256), 256, 0, stream>>>(rp, cnt, N);
    fill_csr_kernel<<<CDIV(E, 1024), 256, 0, stream>>>(src, dst, cnt, col, E);

    const int GG = CDIV(N, 128);  // gemm grid (128 rows/block)

    // --- layer 1 ---
    mfma_gemm<256, 128><<<GG, 256, 0, stream>>>(x, w1h, w1l, dinv, hsbuf, N);
    agg_kernel<128, true><<<CDIV(N, 16), 256, 0, stream>>>(hsbuf, rp, col, dinv, b1, zbuf, N);

    // --- layer 2 ---
    mfma_gemm<128, 128><<<GG, 256, 0, stream>>>(zbuf, w2h, w2l, dinv, hsbuf, N);
    agg_kernel<128, true><<<CDIV(N, 16), 256, 0, stream>>>(hsbuf, rp, col, dinv, b2, zbuf, N);

    // --- layer 3 ---
    mfma_gemm<128, 64><<<GG, 256, 0, stream>>>(zbuf, w3h, w3l, dinv, hsbuf, N);
    agg_kernel<64, true><<<CDIV(N, 32), 256, 0, stream>>>(hsbuf, rp, col, dinv, b3, zbuf, N);

    // --- layer 4 ---
    mfma_gemm<64, 32><<<GG, 256, 0, stream>>>(zbuf, w4h, w4l, dinv, hsbuf, N);
    agg_kernel<32, false><<<CDIV(N, 64), 256, 0, stream>>>(hsbuf, rp, col, dinv, b4, out, N);
}